// Round 9
// baseline (686.743 us; speedup 1.0000x reference)
//
#include <hip/hip_runtime.h>
#include <hip/hip_bf16.h>
#include <hip/hip_cooperative_groups.h>

namespace cg = cooperative_groups;

typedef __attribute__((ext_vector_type(8))) short short8;
typedef __attribute__((ext_vector_type(4))) float f32x4;

__device__ inline float b2f(unsigned short u) {
    union { unsigned int i; float f; } c; c.i = ((unsigned int)u) << 16; return c.f;
}
__device__ inline unsigned short f2b(float f) {
    __hip_bfloat16 h = __float2bfloat16(f);
    return *reinterpret_cast<unsigned short*>(&h);
}

// async global->LDS, 16 B per lane; LDS dest = wave-uniform base + lane*16
__device__ inline void gl_lds16(const unsigned short* g, unsigned short* ldsbase) {
    __builtin_amdgcn_global_load_lds(
        (const __attribute__((address_space(1))) unsigned int*)(g),
        (__attribute__((address_space(3))) unsigned int*)(ldsbase),
        16, 0, 0);
}

struct Params {
    const float *x, *Wq, *bq, *Wk, *bk, *Wv, *bv, *Wo, *bo;
    float* out;
    unsigned short *xb, *Wqt, *Wkt, *Wot, *Wvb, *Wvot, *Q, *Km, *Vot, *S;
    float* bvo;
};

// 128x128-tile GEMM job: C = scale * A[128 rows @ m0] @ Bt[128 rows @ n0]^T + bias
// OMODE 0: bf16 row-major; 1: fp32 row-major; 2: bf16 transposed (C[n*ldc+m])
template<int OMODE>
__device__ __forceinline__ void gemm128_dev(
    const unsigned short* __restrict__ A, const unsigned short* __restrict__ Bt,
    const float* __restrict__ bias, void* __restrict__ Cv,
    int m0, int n0, int Keff, int lda, int ldb, int ldc, long cbase, float scale,
    unsigned short* As, unsigned short* Bs)
{
    const int t = threadIdx.x, lane = t & 63, w = t >> 6;
    const int wr = w >> 1, wc = w & 1;
    const int lrow = lane & 15, quad = lane >> 4;

    f32x4 acc[4][4];
    #pragma unroll
    for (int i = 0; i < 4; i++)
        #pragma unroll
        for (int j = 0; j < 4; j++)
            acc[i][j] = (f32x4){0.f, 0.f, 0.f, 0.f};

    const unsigned short* gA = A  + (long)(m0 + w * 32 + (lane >> 2)) * lda + (lane & 3) * 8;
    const unsigned short* gB = Bt + (long)(n0 + w * 32 + (lane >> 2)) * ldb + (lane & 3) * 8;

    for (int k0 = 0; k0 < Keff; k0 += 64) {
        #pragma unroll
        for (int p2 = 0; p2 < 2; p2++)
            #pragma unroll
            for (int h = 0; h < 2; h++) {
                gl_lds16(gA + (long)h * 16 * lda + k0 + p2 * 32,
                         &As[p2 * 4096 + (w * 32 + h * 16) * 32]);
                gl_lds16(gB + (long)h * 16 * ldb + k0 + p2 * 32,
                         &Bs[p2 * 4096 + (w * 32 + h * 16) * 32]);
            }
        __syncthreads();
        #pragma unroll
        for (int p2 = 0; p2 < 2; p2++) {
            short8 af[4], bfr[4];
            #pragma unroll
            for (int mi = 0; mi < 4; mi++)
                af[mi] = *(const short8*)&As[p2 * 4096 + (wr * 64 + mi * 16 + lrow) * 32 + quad * 8];
            #pragma unroll
            for (int ni = 0; ni < 4; ni++)
                bfr[ni] = *(const short8*)&Bs[p2 * 4096 + (wc * 64 + ni * 16 + lrow) * 32 + quad * 8];
            #pragma unroll
            for (int mi = 0; mi < 4; mi++)
                #pragma unroll
                for (int ni = 0; ni < 4; ni++)
                    acc[mi][ni] = __builtin_amdgcn_mfma_f32_16x16x32_bf16(
                        af[mi], bfr[ni], acc[mi][ni], 0, 0, 0);
        }
        __syncthreads();
    }

    #pragma unroll
    for (int mi = 0; mi < 4; mi++) {
        const int m = m0 + wr * 64 + mi * 16 + quad * 4;
        #pragma unroll
        for (int ni = 0; ni < 4; ni++) {
            const int n = n0 + wc * 64 + ni * 16 + lrow;
            const float bvl = bias ? bias[n] : 0.f;
            #pragma unroll
            for (int rg = 0; rg < 4; rg++) {
                const float val = acc[mi][ni][rg] * scale + bvl;
                if (OMODE == 1)
                    ((float*)Cv)[cbase + (long)(m + rg) * ldc + n] = val;
                else if (OMODE == 2)
                    ((unsigned short*)Cv)[cbase + (long)n * ldc + (m + rg)] = f2b(val);
                else
                    ((unsigned short*)Cv)[cbase + (long)(m + rg) * ldc + n] = f2b(val);
            }
        }
    }
}

// ---------- phases (grid-size agnostic job loops) ----------

__device__ void phase_prep(const Params& p, int bid, int nb, unsigned short* As)
{
    const int t = threadIdx.x;
    // weight transposes Wq,Wk,Wo -> bf16 (3*1024 tile jobs), via LDS 32x33 fp32 tile
    {
        float* tile = (float*)As;
        const int tx = t & 31, ty = t >> 5;
        for (int j = bid; j < 3072; j += nb) {
            const float* src = (j < 1024) ? p.Wq : (j < 2048) ? p.Wk : p.Wo;
            unsigned short* dst = (j < 1024) ? p.Wqt : (j < 2048) ? p.Wkt : p.Wot;
            const int ji = j & 1023;
            const int c0 = (ji & 31) * 32, r0 = (ji >> 5) * 32;
            #pragma unroll
            for (int i = ty; i < 32; i += 8)
                tile[i * 33 + tx] = src[(long)(r0 + i) * 1024 + c0 + tx];
            __syncthreads();
            #pragma unroll
            for (int i = ty; i < 32; i += 8)
                dst[(long)(c0 + i) * 1024 + r0 + tx] = f2b(tile[tx * 33 + i]);
            __syncthreads();
        }
    }
    // x -> xb bf16 (2,097,152 float4)
    for (int i = bid * 256 + t; i < 2097152; i += nb * 256) {
        float4 v = ((const float4*)p.x)[i];
        union { unsigned short u[4]; unsigned long long ll; } pk;
        pk.u[0] = f2b(v.x); pk.u[1] = f2b(v.y); pk.u[2] = f2b(v.z); pk.u[3] = f2b(v.w);
        ((unsigned long long*)p.xb)[i] = pk.ll;
    }
    // Wv -> Wvb bf16 plain (262,144 float4)
    for (int i = bid * 256 + t; i < 262144; i += nb * 256) {
        float4 v = ((const float4*)p.Wv)[i];
        union { unsigned short u[4]; unsigned long long ll; } pk;
        pk.u[0] = f2b(v.x); pk.u[1] = f2b(v.y); pk.u[2] = f2b(v.z); pk.u[3] = f2b(v.w);
        ((unsigned long long*)p.Wvb)[i] = pk.ll;
    }
    // bvo[n] = bv @ Wo[:,n] + bo[n]  (fp32, coalesced across n)
    for (int n = bid * 256 + t; n < 1024; n += nb * 256) {
        float acc = p.bo[n];
        #pragma unroll 8
        for (int k = 0; k < 1024; k++) acc += p.bv[k] * p.Wo[(long)k * 1024 + n];
        p.bvo[n] = acc;
    }
}

__device__ void phase_wvo(const Params& p, int bid, int nb,
                          unsigned short* As, unsigned short* Bs)
{
    // Wvo^T = Wo^T @ Wv^T : A = Wot, Bt = Wvb  (64 jobs)
    for (int j = bid; j < 64; j += nb)
        gemm128_dev<0>(p.Wot, p.Wvb, nullptr, p.Wvot, (j >> 3) * 128, (j & 7) * 128,
                       1024, 1024, 1024, 1024, 0, 1.f, As, Bs);
}

__device__ void phase_qkv(const Params& p, int bid, int nb,
                          unsigned short* As, unsigned short* Bs)
{
    for (int j = bid; j < 1536; j += nb) {
        const int r = j >> 9, inner = j & 511;
        const int m0 = (inner >> 3) * 128, n0 = (inner & 7) * 128;
        if (r == 0)
            gemm128_dev<0>(p.xb, p.Wqt, p.bq, p.Q, m0, n0, 1024, 1024, 1024, 1024, 0, 1.f, As, Bs);
        else if (r == 1)
            gemm128_dev<0>(p.xb, p.Wkt, p.bk, p.Km, m0, n0, 1024, 1024, 1024, 1024, 0, 1.f, As, Bs);
        else
            gemm128_dev<2>(p.xb, p.Wvot, nullptr, p.Vot, m0, n0, 1024, 1024, 1024, 8192, 0, 1.f, As, Bs);
    }
}

__device__ void phase_qk(const Params& p, int bid, int nb,
                         unsigned short* As, unsigned short* Bs)
{
    for (int j = bid; j < 544; j += nb) {
        const int bz = j & 3, q = j >> 2;
        int bm = (int)((sqrtf(8.f * q + 1.f) - 1.f) * 0.5f);
        while ((bm + 1) * (bm + 2) / 2 <= q) bm++;
        while (bm * (bm + 1) / 2 > q) bm--;
        const int bn = q - bm * (bm + 1) / 2;
        gemm128_dev<0>(p.Q + (long)bz * 2048 * 1024, p.Km + (long)bz * 2048 * 1024,
                       nullptr, p.S, bm * 128, bn * 128, 1024, 1024, 1024, 2048,
                       (long)bz * 2048 * 2048, 0.03125f, As, Bs);
    }
}

__device__ void phase_softmax(const Params& p, int bid, int nb, float* red)
{
    const int t = threadIdx.x;
    for (int row = bid; row < 8192; row += nb) {
        const int i = row & 2047;
        unsigned short* base = p.S + (long)row * 2048;
        const int padded = ((i >> 7) + 1) << 7;
        const int j0 = t * 8;
        const bool active = j0 < padded;

        float v[8];
        if (active) {
            short8 s8 = *(const short8*)(base + j0);
            #pragma unroll
            for (int jj = 0; jj < 8; jj++)
                v[jj] = (j0 + jj <= i) ? b2f((unsigned short)s8[jj]) : -3.0e38f;
        } else {
            #pragma unroll
            for (int jj = 0; jj < 8; jj++) v[jj] = -3.0e38f;
        }

        float lmax = v[0];
        #pragma unroll
        for (int jj = 1; jj < 8; jj++) lmax = fmaxf(lmax, v[jj]);
        #pragma unroll
        for (int off = 32; off > 0; off >>= 1) lmax = fmaxf(lmax, __shfl_xor(lmax, off, 64));
        if ((t & 63) == 0) red[t >> 6] = lmax;
        __syncthreads();
        const float gmax = fmaxf(fmaxf(red[0], red[1]), fmaxf(red[2], red[3]));
        __syncthreads();

        float lsum = 0.f;
        #pragma unroll
        for (int jj = 0; jj < 8; jj++) {
            v[jj] = (v[jj] > -1.0e37f) ? __expf(v[jj] - gmax) : 0.f;
            lsum += v[jj];
        }
        #pragma unroll
        for (int off = 32; off > 0; off >>= 1) lsum += __shfl_xor(lsum, off, 64);
        if ((t & 63) == 0) red[t >> 6] = lsum;
        __syncthreads();
        const float inv = 1.0f / (red[0] + red[1] + red[2] + red[3]);

        if (active) {
            short8 p8;
            #pragma unroll
            for (int jj = 0; jj < 8; jj++) p8[jj] = (short)f2b(v[jj] * inv);
            *(short8*)(base + j0) = p8;
        }
        __syncthreads();   // protect red before next row
    }
}

__device__ void phase_pv(const Params& p, int bid, int nb,
                         unsigned short* As, unsigned short* Bs)
{
    for (int j = bid; j < 512; j += nb) {
        const int bz = j & 3, bn = (j >> 2) & 7, bm = 15 - (j >> 5);   // heavy first
        int Keff = (bm + 1) * 128; if (Keff > 2048) Keff = 2048;
        gemm128_dev<1>(p.S + (long)bz * 2048 * 2048, p.Vot + (long)bz * 2048,
                       p.bvo, p.out, bm * 128, bn * 128, Keff, 2048, 8192, 1024,
                       (long)bz * 2048 * 1024, 1.f, As, Bs);
    }
}

// ---------- single persistent cooperative kernel ----------
__global__ void __launch_bounds__(256) attn_all(Params p)
{
    __shared__ __attribute__((aligned(16))) unsigned short As[2 * 128 * 32];
    __shared__ __attribute__((aligned(16))) unsigned short Bs[2 * 128 * 32];
    cg::grid_group grid = cg::this_grid();
    const int bid = blockIdx.x, nb = gridDim.x;

    phase_prep(p, bid, nb, As);           grid.sync();
    phase_wvo(p, bid, nb, As, Bs);        grid.sync();
    phase_qkv(p, bid, nb, As, Bs);        grid.sync();
    phase_qk(p, bid, nb, As, Bs);         grid.sync();
    phase_softmax(p, bid, nb, (float*)As); grid.sync();
    phase_pv(p, bid, nb, As, Bs);
}

// ---------- fallback wrappers (used only if cooperative launch unavailable) ----------
__global__ void __launch_bounds__(256) k_prep(Params p) {
    __shared__ __attribute__((aligned(16))) unsigned short As[2 * 128 * 32];
    phase_prep(p, blockIdx.x, gridDim.x, As);
}
__global__ void __launch_bounds__(256) k_wvo(Params p) {
    __shared__ __attribute__((aligned(16))) unsigned short As[2 * 128 * 32];
    __shared__ __attribute__((aligned(16))) unsigned short Bs[2 * 128 * 32];
    phase_wvo(p, blockIdx.x, gridDim.x, As, Bs);
}
__global__ void __launch_bounds__(256) k_qkv(Params p) {
    __shared__ __attribute__((aligned(16))) unsigned short As[2 * 128 * 32];
    __shared__ __attribute__((aligned(16))) unsigned short Bs[2 * 128 * 32];
    phase_qkv(p, blockIdx.x, gridDim.x, As, Bs);
}
__global__ void __launch_bounds__(256) k_qk(Params p) {
    __shared__ __attribute__((aligned(16))) unsigned short As[2 * 128 * 32];
    __shared__ __attribute__((aligned(16))) unsigned short Bs[2 * 128 * 32];
    phase_qk(p, blockIdx.x, gridDim.x, As, Bs);
}
__global__ void __launch_bounds__(256) k_softmax(Params p) {
    __shared__ float red[4];
    phase_softmax(p, blockIdx.x, gridDim.x, red);
}
__global__ void __launch_bounds__(256) k_pv(Params p) {
    __shared__ __attribute__((aligned(16))) unsigned short As[2 * 128 * 32];
    __shared__ __attribute__((aligned(16))) unsigned short Bs[2 * 128 * 32];
    phase_pv(p, blockIdx.x, gridDim.x, As, Bs);
}

extern "C" void kernel_launch(void* const* d_in, const int* in_sizes, int n_in,
                              void* d_out, int out_size, void* d_ws, size_t ws_size,
                              hipStream_t stream)
{
    unsigned short* ws = (unsigned short*)d_ws;
    const long XSZ = 8192L * 1024;
    const long WSZ = 1024L * 1024;

    Params p;
    p.x  = (const float*)d_in[0];
    p.Wq = (const float*)d_in[2];  p.bq = (const float*)d_in[3];
    p.Wk = (const float*)d_in[4];  p.bk = (const float*)d_in[5];
    p.Wv = (const float*)d_in[6];  p.bv = (const float*)d_in[7];
    p.Wo = (const float*)d_in[8];  p.bo = (const float*)d_in[9];
    p.out = (float*)d_out;
    p.xb   = ws;
    p.Wqt  = ws + XSZ;
    p.Wkt  = p.Wqt + WSZ;
    p.Wot  = p.Wkt + WSZ;
    p.Wvb  = p.Wot + WSZ;
    p.Wvot = p.Wvb + WSZ;
    p.Q    = p.Wvot + WSZ;
    p.Km   = p.Q + XSZ;
    p.Vot  = p.Km + XSZ;                      // [1024, 8192], col m = b*2048 + n
    p.S    = p.Vot + XSZ;                     // [4][2048,2048], S -> P in place
    p.bvo  = (float*)(p.S + 4L * 2048 * 2048);

    int nbpm = 0;
    hipError_t qe = hipOccupancyMaxActiveBlocksPerMultiprocessor(&nbpm, attn_all, 256, 0);
    int grid = (qe == hipSuccess && nbpm > 0) ? nbpm * 256 : 0;
    if (grid > 768) grid = 768;               // 3 blocks/CU: qkv = 2 balanced rounds

    bool coop_ok = false;
    if (grid >= 256) {
        void* args[] = { (void*)&p };
        hipError_t le = hipLaunchCooperativeKernel(attn_all, dim3(grid), dim3(256),
                                                   args, 0, stream);
        coop_ok = (le == hipSuccess);
        if (!coop_ok) (void)hipGetLastError();  // clear error state
    }
    if (!coop_ok) {
        const dim3 blk(256);
        k_prep   <<<dim3(768),  blk, 0, stream>>>(p);
        k_wvo    <<<dim3(64),   blk, 0, stream>>>(p);
        k_qkv    <<<dim3(1536), blk, 0, stream>>>(p);
        k_qk     <<<dim3(544),  blk, 0, stream>>>(p);
        k_softmax<<<dim3(8192), blk, 0, stream>>>(p);
        k_pv     <<<dim3(512),  blk, 0, stream>>>(p);
    }
}

// Round 10
// 633.879 us; speedup vs baseline: 1.0834x; 1.0834x over previous
//
#include <hip/hip_runtime.h>
#include <hip/hip_bf16.h>

typedef __attribute__((ext_vector_type(8))) short short8;
typedef __attribute__((ext_vector_type(4))) float f32x4;

__device__ inline float b2f(unsigned short u) {
    union { unsigned int i; float f; } c; c.i = ((unsigned int)u) << 16; return c.f;
}
__device__ inline unsigned short f2b(float f) {
    __hip_bfloat16 h = __float2bfloat16(f);
    return *reinterpret_cast<unsigned short*>(&h);
}

// async global->LDS, 16 B per lane; LDS dest = wave-uniform base + lane*16
__device__ inline void gl_lds16(const unsigned short* g, unsigned short* ldsbase) {
    __builtin_amdgcn_global_load_lds(
        (const __attribute__((address_space(1))) unsigned int*)(g),
        (__attribute__((address_space(3))) unsigned int*)(ldsbase),
        16, 0, 0);
}

// ---- fused prep: weight transposes, x/Wv bf16 converts, bvo, ticket zero ----
__global__ __launch_bounds__(256) void prep(
    const float* __restrict__ x, const float* __restrict__ Wq,
    const float* __restrict__ Wk, const float* __restrict__ Wv,
    const float* __restrict__ Wo, const float* __restrict__ bv,
    const float* __restrict__ bo,
    unsigned short* __restrict__ xb, unsigned short* __restrict__ Wqt,
    unsigned short* __restrict__ Wkt, unsigned short* __restrict__ Wot,
    unsigned short* __restrict__ Wvb, float* __restrict__ bvo,
    unsigned int* __restrict__ tick)
{
    const int bid = blockIdx.x, nb = gridDim.x, t = threadIdx.x;
    __shared__ float tile[32 * 33];

    // (a) Wq/Wk/Wo fp32 -> bf16 transposed (3072 32x32-tile jobs)
    for (int j = bid; j < 3072; j += nb) {
        const float* src = (j < 1024) ? Wq : (j < 2048) ? Wk : Wo;
        unsigned short* dst = (j < 1024) ? Wqt : (j < 2048) ? Wkt : Wot;
        const int ji = j & 1023;
        const int c0 = (ji & 31) * 32, r0 = (ji >> 5) * 32;
        const int tx = t & 31, ty = t >> 5;
        #pragma unroll
        for (int i2 = ty; i2 < 32; i2 += 8)
            tile[i2 * 33 + tx] = src[(long)(r0 + i2) * 1024 + c0 + tx];
        __syncthreads();
        #pragma unroll
        for (int i2 = ty; i2 < 32; i2 += 8)
            dst[(long)(c0 + i2) * 1024 + r0 + tx] = f2b(tile[tx * 33 + i2]);
        __syncthreads();
    }
    // (b) x -> xb bf16 (2,097,152 float4)
    for (long i = (long)bid * 256 + t; i < 2097152; i += (long)nb * 256) {
        float4 v = ((const float4*)x)[i];
        union { unsigned short u[4]; unsigned long long ll; } pk;
        pk.u[0] = f2b(v.x); pk.u[1] = f2b(v.y); pk.u[2] = f2b(v.z); pk.u[3] = f2b(v.w);
        ((unsigned long long*)xb)[i] = pk.ll;
    }
    // (c) Wv -> Wvb bf16 plain (262,144 float4)
    for (long i = (long)bid * 256 + t; i < 262144; i += (long)nb * 256) {
        float4 v = ((const float4*)Wv)[i];
        union { unsigned short u[4]; unsigned long long ll; } pk;
        pk.u[0] = f2b(v.x); pk.u[1] = f2b(v.y); pk.u[2] = f2b(v.z); pk.u[3] = f2b(v.w);
        ((unsigned long long*)Wvb)[i] = pk.ll;
    }
    // (d) bvo[n] = bv @ Wo[:,n] + bo[n]  (blocks 3072..3075, coalesced across n)
    if (bid >= 3072 && bid < 3076) {
        const int n = (bid - 3072) * 256 + t;
        float acc = bo[n];
        #pragma unroll 8
        for (int k = 0; k < 1024; k++) acc += bv[k] * Wo[(long)k * 1024 + n];
        bvo[n] = acc;
    }
    // (e) zero softmax tickets
    if (bid == nb - 1 && t < 64) tick[t] = 0u;
}

// ---- 128x128 tile machinery (BK=64, two 32-k panels per barrier) ----
#define TILE_DECLS \
    __shared__ __attribute__((aligned(16))) unsigned short As[2 * 128 * 32]; \
    __shared__ __attribute__((aligned(16))) unsigned short Bs[2 * 128 * 32]; \
    const int t = threadIdx.x, lane = t & 63, w = t >> 6; \
    const int wr = w >> 1, wc = w & 1; \
    const int lrow = lane & 15, quad = lane >> 4; \
    f32x4 acc[4][4]; \
    _Pragma("unroll") for (int i = 0; i < 4; i++) \
        _Pragma("unroll") for (int j = 0; j < 4; j++) \
            acc[i][j] = (f32x4){0.f, 0.f, 0.f, 0.f};

#define TILE_KLOOP(gA, lda, gB, ldb, Keff) \
    for (int k0 = 0; k0 < (Keff); k0 += 64) { \
        _Pragma("unroll") for (int p = 0; p < 2; p++) \
            _Pragma("unroll") for (int h = 0; h < 2; h++) { \
                gl_lds16((gA) + (long)h * 16 * (lda) + k0 + p * 32, \
                         &As[p * 4096 + (w * 32 + h * 16) * 32]); \
                gl_lds16((gB) + (long)h * 16 * (ldb) + k0 + p * 32, \
                         &Bs[p * 4096 + (w * 32 + h * 16) * 32]); \
            } \
        __syncthreads(); \
        _Pragma("unroll") for (int p = 0; p < 2; p++) { \
            short8 af[4], bfr[4]; \
            _Pragma("unroll") for (int mi = 0; mi < 4; mi++) \
                af[mi] = *(const short8*)&As[p * 4096 + (wr * 64 + mi * 16 + lrow) * 32 + quad * 8]; \
            _Pragma("unroll") for (int ni = 0; ni < 4; ni++) \
                bfr[ni] = *(const short8*)&Bs[p * 4096 + (wc * 64 + ni * 16 + lrow) * 32 + quad * 8]; \
            _Pragma("unroll") for (int mi = 0; mi < 4; mi++) \
                _Pragma("unroll") for (int ni = 0; ni < 4; ni++) \
                    acc[mi][ni] = __builtin_amdgcn_mfma_f32_16x16x32_bf16( \
                        af[mi], bfr[ni], acc[mi][ni], 0, 0, 0); \
        } \
        __syncthreads(); \
    }

// Fused QKV projection: x[8192,1024] @ {Wq,Wk,Wvo} -> Q, K (row-major, +bias), Vot (transposed)
__global__ __launch_bounds__(256) void qkv_proj(
    const unsigned short* __restrict__ A,
    const unsigned short* __restrict__ Wqt, const unsigned short* __restrict__ Wkt,
    const unsigned short* __restrict__ Wvot,
    const float* __restrict__ bq, const float* __restrict__ bk,
    unsigned short* __restrict__ Q, unsigned short* __restrict__ Km,
    unsigned short* __restrict__ Vot)
{
    const int bm = blockIdx.x, bn = blockIdx.y;
    const int r = bn >> 3, bnn = bn & 7;
    const unsigned short* Bt = (r == 0) ? Wqt : (r == 1) ? Wkt : Wvot;
    const float* bias = (r == 0) ? bq : (r == 1) ? bk : nullptr;
    const int m0 = bm * 128, n0 = bnn * 128;

    TILE_DECLS

    const unsigned short* gA = A  + (long)(m0 + w * 32 + (lane >> 2)) * 1024 + (lane & 3) * 8;
    const unsigned short* gB = Bt + (long)(n0 + w * 32 + (lane >> 2)) * 1024 + (lane & 3) * 8;
    TILE_KLOOP(gA, 1024, gB, 1024, 1024)

    #pragma unroll
    for (int mi = 0; mi < 4; mi++) {
        const int m = m0 + wr * 64 + mi * 16 + quad * 4;
        #pragma unroll
        for (int ni = 0; ni < 4; ni++) {
            const int n = n0 + wc * 64 + ni * 16 + lrow;
            const float bvl = bias ? bias[n] : 0.f;
            if (r < 2) {
                unsigned short* out = (r == 0) ? Q : Km;
                #pragma unroll
                for (int rg = 0; rg < 4; rg++)
                    out[(long)(m + rg) * 1024 + n] = f2b(acc[mi][ni][rg] + bvl);
            } else {
                #pragma unroll
                for (int rg = 0; rg < 4; rg++)
                    Vot[(long)n * 8192 + m + rg] = f2b(acc[mi][ni][rg]);
            }
        }
    }
}

// QK^T + ticket-fused causal softmax. Reversed triangular grid (heavy row-blocks first).
__global__ __launch_bounds__(256) void qk_softmax(
    const unsigned short* __restrict__ Q, const unsigned short* __restrict__ Km,
    unsigned short* __restrict__ S, unsigned int* __restrict__ tick)
{
    const int qidx = 135 - (int)blockIdx.x;
    int bm = (int)((sqrtf(8.f * qidx + 1.f) - 1.f) * 0.5f);
    while ((bm + 1) * (bm + 2) / 2 <= qidx) bm++;
    while (bm * (bm + 1) / 2 > qidx) bm--;
    const int bn = qidx - bm * (bm + 1) / 2;
    const int bz = blockIdx.y;

    const unsigned short* A  = Q  + (long)bz * 2048 * 1024;
    const unsigned short* Bt = Km + (long)bz * 2048 * 1024;
    unsigned short* Sb = S + (long)bz * 2048 * 2048;
    const int m0 = bm * 128, n0 = bn * 128;

    __shared__ int sdone;
    TILE_DECLS

    const unsigned short* gA = A  + (long)(m0 + w * 32 + (lane >> 2)) * 1024 + (lane & 3) * 8;
    const unsigned short* gB = Bt + (long)(n0 + w * 32 + (lane >> 2)) * 1024 + (lane & 3) * 8;
    TILE_KLOOP(gA, 1024, gB, 1024, 1024)

    #pragma unroll
    for (int mi = 0; mi < 4; mi++) {
        const int m = m0 + wr * 64 + mi * 16 + quad * 4;
        #pragma unroll
        for (int ni = 0; ni < 4; ni++) {
            const int n = n0 + wc * 64 + ni * 16 + lrow;
            #pragma unroll
            for (int rg = 0; rg < 4; rg++)
                Sb[(long)(m + rg) * 2048 + n] = f2b(acc[mi][ni][rg] * 0.03125f);
        }
    }

    // ticket: last finisher of row-block (bm,bz) softmaxes its 128 rows
    __threadfence();
    __syncthreads();
    if (t == 0) {
        unsigned int old = __hip_atomic_fetch_add(&tick[bz * 16 + bm], 1u,
                               __ATOMIC_ACQ_REL, __HIP_MEMORY_SCOPE_AGENT);
        sdone = (old == (unsigned)bm) ? 1 : 0;
    }
    __syncthreads();
    if (!sdone) return;
    __threadfence();

    const int cols = (bm + 1) * 128;    // uniform padded boundary for this row-block
    for (int r = w; r < 128; r += 4) {
        const int i = m0 + r;
        unsigned short* base = Sb + (long)i * 2048;
        const int len = i + 1;
        float mx = -3.0e38f;
        for (int c = lane * 8; c < cols; c += 512) {
            short8 v = *(const short8*)(base + c);
            #pragma unroll
            for (int j = 0; j < 8; j++)
                if (c + j < len) mx = fmaxf(mx, b2f((unsigned short)v[j]));
        }
        #pragma unroll
        for (int off = 32; off > 0; off >>= 1) mx = fmaxf(mx, __shfl_xor(mx, off, 64));
        float sum = 0.f;
        for (int c = lane * 8; c < cols; c += 512) {
            short8 v = *(const short8*)(base + c);
            #pragma unroll
            for (int j = 0; j < 8; j++)
                if (c + j < len) sum += __expf(b2f((unsigned short)v[j]) - mx);
        }
        #pragma unroll
        for (int off = 32; off > 0; off >>= 1) sum += __shfl_xor(sum, off, 64);
        const float inv = 1.0f / sum;
        for (int c = lane * 8; c < cols; c += 512) {
            short8 v = *(const short8*)(base + c);
            short8 o;
            #pragma unroll
            for (int j = 0; j < 8; j++)
                o[j] = (c + j < len)
                    ? (short)f2b(__expf(b2f((unsigned short)v[j]) - mx) * inv)
                    : (short)0;
            *(short8*)(base + c) = o;
        }
    }
}

// 128x128 GEMM for PV / generic: C = scale * A @ Bt^T + bias
//  KCAUSAL: Keff = (bm+1)*128 capped, bm order reversed (heavy first). OMODE 0 bf16 / 1 fp32.
template<bool KCAUSAL, int OMODE>
__global__ __launch_bounds__(256) void gemm128(
    const unsigned short* __restrict__ A, const unsigned short* __restrict__ Bt,
    const float* __restrict__ bias, void* __restrict__ Cv,
    int K, int lda, int ldb, int ldc, long sA, long sB, long sC, float scale)
{
    const int bm = KCAUSAL ? (gridDim.x - 1 - blockIdx.x) : blockIdx.x;
    const int bn = blockIdx.y, bz = blockIdx.z;
    A  += (long)bz * sA;
    Bt += (long)bz * sB;
    const int m0 = bm * 128, n0 = bn * 128;

    TILE_DECLS

    const int KeffRaw = KCAUSAL ? (bm + 1) * 128 : K;
    const int Keff = KeffRaw < K ? KeffRaw : K;
    const unsigned short* gA = A  + (long)(m0 + w * 32 + (lane >> 2)) * lda + (lane & 3) * 8;
    const unsigned short* gB = Bt + (long)(n0 + w * 32 + (lane >> 2)) * ldb + (lane & 3) * 8;
    TILE_KLOOP(gA, lda, gB, ldb, Keff)

    #pragma unroll
    for (int mi = 0; mi < 4; mi++) {
        const int m = m0 + wr * 64 + mi * 16 + quad * 4;
        #pragma unroll
        for (int ni = 0; ni < 4; ni++) {
            const int n = n0 + wc * 64 + ni * 16 + lrow;
            const float bvl = bias ? bias[n] : 0.f;
            #pragma unroll
            for (int rg = 0; rg < 4; rg++) {
                const float val = acc[mi][ni][rg] * scale + bvl;
                if (OMODE == 1)
                    ((float*)Cv)[(long)bz * sC + (long)(m + rg) * ldc + n] = val;
                else
                    ((unsigned short*)Cv)[(long)bz * sC + (long)(m + rg) * ldc + n] = f2b(val);
            }
        }
    }
}

// 64x128-tile GEMM (for the small Wvo fold: 128 blocks instead of 64)
__global__ __launch_bounds__(256) void gemm64w(
    const unsigned short* __restrict__ A, const unsigned short* __restrict__ Bt,
    unsigned short* __restrict__ C)
{
    const int m0 = blockIdx.x * 64, n0 = blockIdx.y * 128;

    __shared__ __attribute__((aligned(16))) unsigned short As[2 * 64 * 32];
    __shared__ __attribute__((aligned(16))) unsigned short Bs[2 * 128 * 32];

    const int t = threadIdx.x, lane = t & 63, w = t >> 6;
    const int wr = w >> 1, wc = w & 1;
    const int lrow = lane & 15, quad = lane >> 4;

    f32x4 acc[2][4];
    #pragma unroll
    for (int i = 0; i < 2; i++)
        #pragma unroll
        for (int j = 0; j < 4; j++)
            acc[i][j] = (f32x4){0.f, 0.f, 0.f, 0.f};

    const unsigned short* gA = A  + (long)(m0 + w * 16 + (lane >> 2)) * 1024 + (lane & 3) * 8;
    const unsigned short* gB = Bt + (long)(n0 + w * 32 + (lane >> 2)) * 1024 + (lane & 3) * 8;

    for (int k0 = 0; k0 < 1024; k0 += 64) {
        #pragma unroll
        for (int p = 0; p < 2; p++) {
            gl_lds16(gA + k0 + p * 32, &As[p * 2048 + (w * 16) * 32]);
            gl_lds16(gB + k0 + p * 32, &Bs[p * 4096 + (w * 32) * 32]);
            gl_lds16(gB + (long)16 * 1024 + k0 + p * 32, &Bs[p * 4096 + (w * 32 + 16) * 32]);
        }
        __syncthreads();
        #pragma unroll
        for (int p = 0; p < 2; p++) {
            short8 af[2], bfr[4];
            #pragma unroll
            for (int mi = 0; mi < 2; mi++)
                af[mi] = *(const short8*)&As[p * 2048 + (wr * 32 + mi * 16 + lrow) * 32 + quad * 8];
            #pragma unroll
            for (int ni = 0; ni < 4; ni++)
                bfr[ni] = *(const short8*)&Bs[p * 4096 + (wc * 64 + ni * 16 + lrow) * 32 + quad * 8];
            #pragma unroll
            for (int mi = 0; mi < 2; mi++)
                #pragma unroll
                for (int ni = 0; ni < 4; ni++)
                    acc[mi][ni] = __builtin_amdgcn_mfma_f32_16x16x32_bf16(
                        af[mi], bfr[ni], acc[mi][ni], 0, 0, 0);
        }
        __syncthreads();
    }

    #pragma unroll
    for (int mi = 0; mi < 2; mi++) {
        const int m = m0 + wr * 32 + mi * 16 + quad * 4;
        #pragma unroll
        for (int ni = 0; ni < 4; ni++) {
            const int n = n0 + wc * 64 + ni * 16 + lrow;
            #pragma unroll
            for (int rg = 0; rg < 4; rg++)
                C[(long)(m + rg) * 1024 + n] = f2b(acc[mi][ni][rg]);
        }
    }
}

extern "C" void kernel_launch(void* const* d_in, const int* in_sizes, int n_in,
                              void* d_out, int out_size, void* d_ws, size_t ws_size,
                              hipStream_t stream)
{
    // inputs (fp32): x, mask(ignored - known causal), Wq, bq, Wk, bk, Wv, bv, Wo, bo
    const float* x  = (const float*)d_in[0];
    const float* Wq = (const float*)d_in[2];
    const float* bq = (const float*)d_in[3];
    const float* Wk = (const float*)d_in[4];
    const float* bk = (const float*)d_in[5];
    const float* Wv = (const float*)d_in[6];
    const float* bv = (const float*)d_in[7];
    const float* Wo = (const float*)d_in[8];
    const float* bo = (const float*)d_in[9];

    unsigned short* ws = (unsigned short*)d_ws;
    const long XSZ = 8192L * 1024;
    const long WSZ = 1024L * 1024;
    unsigned short* xb   = ws;                // [8192,1024] bf16
    unsigned short* Wqt  = ws + XSZ;          // Wq^T
    unsigned short* Wkt  = Wqt + WSZ;
    unsigned short* Wot  = Wkt + WSZ;
    unsigned short* Wvb  = Wot + WSZ;         // Wv plain bf16
    unsigned short* Wvot = Wvb + WSZ;         // (Wv@Wo)^T
    unsigned short* Q    = Wvot + WSZ;        // [8192,1024]
    unsigned short* Km   = Q + XSZ;           // [8192,1024]
    unsigned short* Vot  = Km + XSZ;          // [1024,8192], col m = b*2048+n
    unsigned short* S    = Vot + XSZ;         // [4][2048,2048] (S -> P in place)
    float*          bvo  = (float*)(S + 4L * 2048 * 2048);
    unsigned int*   tick = (unsigned int*)(bvo + 1024);   // [64] softmax tickets

    const dim3 blk(256);

    // 1. fused prep
    prep<<<dim3(4096), blk, 0, stream>>>(
        x, Wq, Wk, Wv, Wo, bv, bo, xb, Wqt, Wkt, Wot, Wvb, bvo, tick);

    // 2. Wvo^T = Wo^T @ Wv^T  (128 blocks)
    gemm64w<<<dim3(16, 8), blk, 0, stream>>>(Wot, Wvb, Wvot);

    // 3. fused QKV projection
    qkv_proj<<<dim3(64, 24), blk, 0, stream>>>(
        xb, Wqt, Wkt, Wvot, bq, bk, Q, Km, Vot);

    // 4. QK^T + ticket-fused softmax (544 blocks, heavy row-blocks first)
    qk_softmax<<<dim3(136, 4), blk, 0, stream>>>(Q, Km, S, tick);

    // 5. out = P @ Vo + bvo (fp32)
    gemm128<true, 1><<<dim3(16, 8, 4), blk, 0, stream>>>(
        S, Vot, bvo, (float*)d_out, 2048, 2048, 8192, 1024,
        2048L * 2048, 2048, 2048L * 1024, 1.f);
}